// Round 2
// baseline (375.569 us; speedup 1.0000x reference)
//
#include <hip/hip_runtime.h>

#define DEPTH 25
#define DIM   64
#define HID   100

typedef _Float16 f16x4 __attribute__((ext_vector_type(4)));
typedef _Float16 f16x8 __attribute__((ext_vector_type(8)));
typedef __fp16   h2    __attribute__((ext_vector_type(2)));   // cvt_pkrtz result type
typedef float    f32x4 __attribute__((ext_vector_type(4)));
typedef float    f32x2 __attribute__((ext_vector_type(2)));

// ---- Pre-kernel: Levy noise (Chambers-Mallows-Stuck, alpha=1.8, beta=0) ----
__global__ __launch_bounds__(64) void levy_noise_kernel(
    const float* __restrict__ u_raw, const float* __restrict__ w_raw,
    float* __restrict__ noise)
{
    const int idx = blockIdx.x * 64 + threadIdx.x;
    if (idx >= DEPTH * DIM) return;
    float u = u_raw[idx];
    float w = w_raw[idx];
    float U  = 3.14159265358979323846f * (u - 0.5f);
    float Wv = -logf(fminf(fmaxf(w, 1e-12f), 1.0f));
    float t1 = sinf(1.8f * U) / powf(cosf(U), 0.5555555555555556f);
    float ratio = cosf(0.8f * U) / fmaxf(Wv, 1e-12f);
    float X = t1 * powf(ratio, -0.4444444444444444f);
    noise[idx] = fminf(fmaxf(0.1f * X, -10.0f), 10.0f);
}

// Concatenate two LDS f16x4 reads (ds_read_b64 each) into one MFMA operand.
// Stacked-halves K layout assumed for mfma_f32_16x16x32_f16:
//   elems 0-3 -> k = 4*(lane>>4) + {0..3}, elems 4-7 -> k = 16 + 4*(lane>>4) + {0..3}
static __device__ __forceinline__ f16x8 lda8(const _Float16* p) {
    f16x4 lo = *(const f16x4*)p;
    f16x4 hi = *(const f16x4*)(p + 16);
    f16x8 v;
    v[0] = lo[0]; v[1] = lo[1]; v[2] = lo[2]; v[3] = lo[3];
    v[4] = hi[0]; v[5] = hi[1]; v[6] = hi[2]; v[7] = hi[3];
    return v;
}

// One block = 256 threads = 4 waves; each wave owns 16 batch rows.
// State kept TRANSPOSED (out^T). With the stacked-halves layout, the K=32
// B-fragment kt is exactly C/D tiles Mt=2kt (elems 0-3) and Mt=2kt+1
// (elems 4-7): chaining stays shuffle-free, 8 MFMA/step, chain depth 2.
// Weights staged once per block into LDS as transposed f16 (phase-overlaid).
__global__ __launch_bounds__(256) void sdenet_fused(
    const float* __restrict__ x,      const float* __restrict__ noise_g,
    const float* __restrict__ W_down, const float* __restrict__ b_down,
    const float* __restrict__ W_drift,const float* __restrict__ b_drift,
    const float* __restrict__ W1,     const float* __restrict__ b1,
    const float* __restrict__ W2,     const float* __restrict__ b2,
    float* __restrict__ out, int batch)
{
    __shared__ float    noise_lds[DEPTH * DIM];      // 6400 B
    __shared__ _Float16 wbuf[8192];                  // 16384 B
    // phase A: wbuf[0:4096)   = W_down^T  f16  [m][k]
    //          wbuf[4096:8192)= dt*W_drift^T f16 [m][k]
    // phase B: wbuf[0:7168)   = W1^T f16 [n][k], zero-padded n in [100,112)

    const int tid  = threadIdx.x;
    const int wave = tid >> 6;
    const int lane = tid & 63;
    const int r    = lane & 15;        // batch row within wave tile (B/C col)
    const int g    = lane >> 4;        // 16-lane group 0..3
    const int row  = blockIdx.x * 64 + wave * 16 + r;
    const float dt = 0.04f;

    // ---------- stage noise + W_down^T + dt*W_drift^T (phase A) ----------
    {
        const float4* src = (const float4*)noise_g;
        float4* dst = (float4*)noise_lds;
        for (int idx = tid; idx < DEPTH * DIM / 4; idx += 256)
            dst[idx] = src[idx];
    }
    for (int idx = tid; idx < 2048; idx += 256) {
        const int m = idx >> 5;            // output dim (row of W^T)
        const int k = (idx & 31) * 2;      // input dim (pairs)
        *(h2*)(wbuf + m * 64 + k) =
            __builtin_amdgcn_cvt_pkrtz(W_down[k * DIM + m], W_down[(k + 1) * DIM + m]);
        *(h2*)(wbuf + 4096 + m * 64 + k) =
            __builtin_amdgcn_cvt_pkrtz(dt * W_drift[k * DIM + m],
                                       dt * W_drift[(k + 1) * DIM + m]);
    }

    // prefetch x (global latency overlaps staging drain)
    float4 xlo[2], xhi[2];
    #pragma unroll
    for (int kt = 0; kt < 2; ++kt) {
        xlo[kt] = *(const float4*)(x + row * DIM + kt * 32 + g * 4);
        xhi[kt] = *(const float4*)(x + row * DIM + kt * 32 + 16 + g * 4);
    }
    __syncthreads();

    // ---------- initial: out0^T = W_down^T @ x^T + b_down ----------
    f16x8 bfrag[2];
    #pragma unroll
    for (int kt = 0; kt < 2; ++kt) {
        f16x8 t;
        t[0] = (_Float16)xlo[kt].x; t[1] = (_Float16)xlo[kt].y;
        t[2] = (_Float16)xlo[kt].z; t[3] = (_Float16)xlo[kt].w;
        t[4] = (_Float16)xhi[kt].x; t[5] = (_Float16)xhi[kt].y;
        t[6] = (_Float16)xhi[kt].z; t[7] = (_Float16)xhi[kt].w;
        bfrag[kt] = t;
    }

    f32x2 out2[4][2];   // master fp32 state, C/D layout (dim = Mt*16 + 4g + reg)
    #pragma unroll
    for (int Mt = 0; Mt < 4; ++Mt) {
        f32x4 acc = *(const f32x4*)(b_down + Mt * 16 + g * 4);
        #pragma unroll
        for (int kt = 0; kt < 2; ++kt)
            acc = __builtin_amdgcn_mfma_f32_16x16x32_f16(
                lda8(wbuf + (Mt * 16 + r) * 64 + kt * 32 + g * 4),
                bfrag[kt], acc, 0, 0, 0);
        out2[Mt][0][0] = acc[0]; out2[Mt][0][1] = acc[1];
        out2[Mt][1][0] = acc[2]; out2[Mt][1][1] = acc[3];
    }

    // refresh B fragments from state (RTN casts — keep state rounding unbiased)
    auto refresh = [&]() {
        #pragma unroll
        for (int kt = 0; kt < 2; ++kt) {
            f16x8 t;
            t[0] = (_Float16)out2[2*kt  ][0][0]; t[1] = (_Float16)out2[2*kt  ][0][1];
            t[2] = (_Float16)out2[2*kt  ][1][0]; t[3] = (_Float16)out2[2*kt  ][1][1];
            t[4] = (_Float16)out2[2*kt+1][0][0]; t[5] = (_Float16)out2[2*kt+1][0][1];
            t[6] = (_Float16)out2[2*kt+1][1][0]; t[7] = (_Float16)out2[2*kt+1][1][1];
            bfrag[kt] = t;
        }
    };
    refresh();

    // ---------- persistent dt-scaled drift fragments + dt*bias ----------
    f16x8 aWd[4][2];
    #pragma unroll
    for (int Mt = 0; Mt < 4; ++Mt)
        #pragma unroll
        for (int kt = 0; kt < 2; ++kt)
            aWd[Mt][kt] = lda8(wbuf + 4096 + (Mt * 16 + r) * 64 + kt * 32 + g * 4);

    f32x4 biasd[4];
    #pragma unroll
    for (int Mt = 0; Mt < 4; ++Mt) {
        f32x4 b = *(const f32x4*)(b_drift + Mt * 16 + g * 4);
        biasd[Mt][0] = b[0] * dt; biasd[Mt][1] = b[1] * dt;
        biasd[Mt][2] = b[2] * dt; biasd[Mt][3] = b[3] * dt;
    }

    __syncthreads();   // all waves done with wbuf phase A

    // ---------- stage W1^T (zero-padded 112x64, phase B) ----------
    for (int idx = tid; idx < 3584; idx += 256) {
        const int n = idx >> 5;
        const int k = (idx & 31) * 2;
        const float v0 = (n < HID) ? W1[k * HID + n] : 0.0f;
        const float v1 = (n < HID) ? W1[(k + 1) * HID + n] : 0.0f;
        *(h2*)(wbuf + n * 64 + k) = __builtin_amdgcn_cvt_pkrtz(v0, v1);
    }
    __syncthreads();

    // ---------- head on initial state: logit = relu(out0@W1+b1)@W2 + b2 ----------
    float partial = 0.0f;
    #pragma unroll
    for (int Mt = 0; Mt < 7; ++Mt) {          // HID padded 100 -> 112
        f32x4 acc;
        #pragma unroll
        for (int reg = 0; reg < 4; ++reg) {
            const int n = Mt * 16 + g * 4 + reg;
            acc[reg] = (n < HID) ? b1[n] : 0.0f;
        }
        const int ncol = Mt * 16 + r;
        #pragma unroll
        for (int kt = 0; kt < 2; ++kt)
            acc = __builtin_amdgcn_mfma_f32_16x16x32_f16(
                lda8(wbuf + ncol * 64 + kt * 32 + g * 4), bfrag[kt], acc, 0, 0, 0);
        #pragma unroll
        for (int reg = 0; reg < 4; ++reg) {
            const int n = Mt * 16 + g * 4 + reg;
            if (n < HID) partial += fmaxf(acc[reg], 0.0f) * W2[n];
        }
    }
    partial += __shfl_xor(partial, 16);
    partial += __shfl_xor(partial, 32);
    const float logit = partial + b2[0];
    const float scale = 0.5f * (1.0f / (1.0f + expf(-logit)))
                      * powf(0.04f, 1.0f / 1.8f);
    const f32x2 scale2 = { scale, scale };
    const f32x2 c104   = { 1.04f, 1.04f };
    const f32x2 zero2  = { 0.0f, 0.0f };

    // ---------- 25 SDE steps, all in registers ----------
    for (int t = 0; t < DEPTH; ++t) {
        // noise reads are same-address broadcasts within each 16-lane group
        f32x4 nz[4];
        #pragma unroll
        for (int Mt = 0; Mt < 4; ++Mt)
            nz[Mt] = *(const f32x4*)(noise_lds + t * DIM + Mt * 16 + g * 4);

        f32x4 acc[4];
        #pragma unroll
        for (int Mt = 0; Mt < 4; ++Mt) {
            acc[Mt] = __builtin_amdgcn_mfma_f32_16x16x32_f16(
                aWd[Mt][0], bfrag[0], biasd[Mt], 0, 0, 0);
            acc[Mt] = __builtin_amdgcn_mfma_f32_16x16x32_f16(
                aWd[Mt][1], bfrag[1], acc[Mt], 0, 0, 0);
        }
        // out = fma(scale, nz, fma(out, 1.04, relu(acc_dt_scaled)))  [packed f32]
        #pragma unroll
        for (int Mt = 0; Mt < 4; ++Mt) {
            #pragma unroll
            for (int h = 0; h < 2; ++h) {
                f32x2 a2 = { acc[Mt][2*h], acc[Mt][2*h+1] };
                f32x2 n2 = { nz[Mt][2*h],  nz[Mt][2*h+1] };
                f32x2 rel = __builtin_elementwise_max(a2, zero2);
                f32x2 tmp = __builtin_elementwise_fma(out2[Mt][h], c104, rel);
                out2[Mt][h] = __builtin_elementwise_fma(scale2, n2, tmp);
            }
        }
        refresh();
    }

    // ---- final drift (undo dt scaling: relu(z) = relu(dt*z)*25) + stores ----
    const long long out2_off = (long long)batch * DIM;
    #pragma unroll
    for (int Mt = 0; Mt < 4; ++Mt) {
        f32x4 acc = __builtin_amdgcn_mfma_f32_16x16x32_f16(
            aWd[Mt][0], bfrag[0], biasd[Mt], 0, 0, 0);
        acc = __builtin_amdgcn_mfma_f32_16x16x32_f16(
            aWd[Mt][1], bfrag[1], acc, 0, 0, 0);
        float o0 = out2[Mt][0][0], o1 = out2[Mt][0][1];
        float o2 = out2[Mt][1][0], o3 = out2[Mt][1][1];
        float4 dv, ov;
        dv.x = fmaf(fmaxf(acc[0], 0.0f), 25.0f, o0);
        dv.y = fmaf(fmaxf(acc[1], 0.0f), 25.0f, o1);
        dv.z = fmaf(fmaxf(acc[2], 0.0f), 25.0f, o2);
        dv.w = fmaf(fmaxf(acc[3], 0.0f), 25.0f, o3);
        ov.x = o0; ov.y = o1; ov.z = o2; ov.w = o3;
        *(float4*)(out + (long long)row * DIM + Mt * 16 + g * 4) = dv;
        *(float4*)(out + out2_off + (long long)row * DIM + Mt * 16 + g * 4) = ov;
    }
}

extern "C" void kernel_launch(void* const* d_in, const int* in_sizes, int n_in,
                              void* d_out, int out_size, void* d_ws, size_t ws_size,
                              hipStream_t stream) {
    const float* x       = (const float*)d_in[0];
    const float* u_raw   = (const float*)d_in[1];
    const float* w_raw   = (const float*)d_in[2];
    const float* W_down  = (const float*)d_in[3];
    const float* b_down  = (const float*)d_in[4];
    const float* W_drift = (const float*)d_in[5];
    const float* b_drift = (const float*)d_in[6];
    const float* W1      = (const float*)d_in[7];
    const float* b1      = (const float*)d_in[8];
    const float* W2      = (const float*)d_in[9];
    const float* b2      = (const float*)d_in[10];
    float* out   = (float*)d_out;
    float* noise = (float*)d_ws;               // 1600 floats scratch

    const int batch = in_sizes[0] / DIM;       // 262144
    const int blocks = batch / 64;

    levy_noise_kernel<<<DEPTH, 64, 0, stream>>>(u_raw, w_raw, noise);
    sdenet_fused<<<blocks, 256, 0, stream>>>(
        x, noise, W_down, b_down, W_drift, b_drift,
        W1, b1, W2, b2, out, batch);
}

// Round 3
// 288.170 us; speedup vs baseline: 1.3033x; 1.3033x over previous
//
#include <hip/hip_runtime.h>

#define DEPTH 25
#define DIM   64
#define HID   100

typedef _Float16 f16x4 __attribute__((ext_vector_type(4)));
typedef _Float16 f16x8 __attribute__((ext_vector_type(8)));
typedef __fp16   h2    __attribute__((ext_vector_type(2)));   // cvt_pkrtz result type
typedef float    f32x4 __attribute__((ext_vector_type(4)));
typedef float    f32x2 __attribute__((ext_vector_type(2)));

// ---- Pre-kernel: Levy noise (Chambers-Mallows-Stuck, alpha=1.8, beta=0) ----
__global__ __launch_bounds__(64) void levy_noise_kernel(
    const float* __restrict__ u_raw, const float* __restrict__ w_raw,
    float* __restrict__ noise)
{
    const int idx = blockIdx.x * 64 + threadIdx.x;
    if (idx >= DEPTH * DIM) return;
    float u = u_raw[idx];
    float w = w_raw[idx];
    float U  = 3.14159265358979323846f * (u - 0.5f);
    float Wv = -logf(fminf(fmaxf(w, 1e-12f), 1.0f));
    float t1 = sinf(1.8f * U) / powf(cosf(U), 0.5555555555555556f);
    float ratio = cosf(0.8f * U) / fmaxf(Wv, 1e-12f);
    float X = t1 * powf(ratio, -0.4444444444444444f);
    noise[idx] = fminf(fmaxf(0.1f * X, -10.0f), 10.0f);
}

// Build an f16x8 MFMA operand from 4 packed cvt_pkrtz results (4 VGPRs).
union frag_u { h2 p[4]; f16x8 v; };

// One block = 256 threads = 4 waves; each wave owns 16 batch rows.
// State kept TRANSPOSED (out^T). mfma_f32_16x16x32_f16 stacked-halves K
// layout (VERIFIED round 2): elems 0-3 -> k = 4g+{0..3}, elems 4-7 ->
// k = 16+4g+{0..3}. C/D tiles Mt=2kt / 2kt+1 pack directly into B-fragment
// kt: chaining is shuffle-free, 8 MFMA/step, chain depth 2.
//
// Weights staged once per block into LDS in FRAGMENT ORDER:
//   frag fi = Mt*2+kt occupies halves [fi*512, fi*512+512); lane l holds
//   halves [fi*512 + l*8, +8) -> one conflict-free ds_read_b128 per operand.
// (Round-2's [m][k] rows at 128 B stride were a 16-way bank conflict:
//  5.9e7 conflict cycles ~= 90 us. Fragment order eliminates them all.)
__global__ __launch_bounds__(256) void sdenet_fused(
    const float* __restrict__ x,      const float* __restrict__ noise_g,
    const float* __restrict__ W_down, const float* __restrict__ b_down,
    const float* __restrict__ W_drift,const float* __restrict__ b_drift,
    const float* __restrict__ W1,     const float* __restrict__ b1,
    const float* __restrict__ W2,     const float* __restrict__ b2,
    float* __restrict__ out, int batch)
{
    __shared__ float    noise_lds[DEPTH * DIM];      // 6400 B
    __shared__ _Float16 wbuf[8192];                  // 16384 B
    // phase A: wbuf[0:4096)    = W_down^T  fragments (fi = Mt*2+kt, 8 frags)
    //          wbuf[4096:8192) = dt*W_drift^T fragments
    // phase B: wbuf[0:7168)    = W1^T fragments (14 frags, n>=100 zero-padded)

    const int tid  = threadIdx.x;
    const int wave = tid >> 6;
    const int lane = tid & 63;
    const int r    = lane & 15;        // batch row within wave tile (B/C col)
    const int g    = lane >> 4;        // 16-lane group 0..3
    const int row  = blockIdx.x * 64 + wave * 16 + r;
    const int fbase = lane * 8;        // per-lane fragment offset (halves)
    const float dt = 0.04f;

    // ---------- stage noise + W_down^T + dt*W_drift^T (phase A) ----------
    {
        const float4* src = (const float4*)noise_g;
        float4* dst = (float4*)noise_lds;
        for (int idx = tid; idx < DEPTH * DIM / 4; idx += 256)
            dst[idx] = src[idx];
    }
    // idx2 indexes h2 pairs; dest half-index = idx2*2 (consecutive tid ->
    // consecutive 4B -> conflict-free writes). Decode (frag,lane,j) -> (m,k).
    for (int idx2 = tid; idx2 < 2048; idx2 += 256) {
        const int fi    = idx2 >> 8;           // fragment 0..7
        const int lane2 = (idx2 >> 2) & 63;
        const int j     = (idx2 & 3) * 2;      // elem pair start 0,2,4,6
        const int m     = (fi >> 1) * 16 + (lane2 & 15);
        const int k     = (fi & 1) * 32 + ((j & 4) ? 16 : 0)
                        + (lane2 >> 4) * 4 + (j & 3);
        *(h2*)(wbuf + idx2 * 2) =
            __builtin_amdgcn_cvt_pkrtz(W_down[k * DIM + m],
                                       W_down[(k + 1) * DIM + m]);
        *(h2*)(wbuf + 4096 + idx2 * 2) =
            __builtin_amdgcn_cvt_pkrtz(dt * W_drift[k * DIM + m],
                                       dt * W_drift[(k + 1) * DIM + m]);
    }

    // prefetch x (global latency overlaps staging drain)
    float4 xlo[2], xhi[2];
    #pragma unroll
    for (int kt = 0; kt < 2; ++kt) {
        xlo[kt] = *(const float4*)(x + row * DIM + kt * 32 + g * 4);
        xhi[kt] = *(const float4*)(x + row * DIM + kt * 32 + 16 + g * 4);
    }
    __syncthreads();

    // ---------- initial: out0^T = W_down^T @ x^T + b_down ----------
    f16x8 bfrag[2];
    #pragma unroll
    for (int kt = 0; kt < 2; ++kt) {
        frag_u u;
        u.p[0] = __builtin_amdgcn_cvt_pkrtz(xlo[kt].x, xlo[kt].y);
        u.p[1] = __builtin_amdgcn_cvt_pkrtz(xlo[kt].z, xlo[kt].w);
        u.p[2] = __builtin_amdgcn_cvt_pkrtz(xhi[kt].x, xhi[kt].y);
        u.p[3] = __builtin_amdgcn_cvt_pkrtz(xhi[kt].z, xhi[kt].w);
        bfrag[kt] = u.v;
    }

    f32x2 out2[4][2];   // master fp32 state, C/D layout (dim = Mt*16 + 4g + reg)
    #pragma unroll
    for (int Mt = 0; Mt < 4; ++Mt) {
        f32x4 acc = *(const f32x4*)(b_down + Mt * 16 + g * 4);
        #pragma unroll
        for (int kt = 0; kt < 2; ++kt)
            acc = __builtin_amdgcn_mfma_f32_16x16x32_f16(
                *(const f16x8*)(wbuf + (Mt * 2 + kt) * 512 + fbase),
                bfrag[kt], acc, 0, 0, 0);
        out2[Mt][0][0] = acc[0]; out2[Mt][0][1] = acc[1];
        out2[Mt][1][0] = acc[2]; out2[Mt][1][1] = acc[3];
    }

    // refresh B fragments from state: 8 packed RTZ converts (was 16 cvt + 8 pack)
    auto refresh = [&]() {
        #pragma unroll
        for (int kt = 0; kt < 2; ++kt) {
            frag_u u;
            u.p[0] = __builtin_amdgcn_cvt_pkrtz(out2[2*kt  ][0][0], out2[2*kt  ][0][1]);
            u.p[1] = __builtin_amdgcn_cvt_pkrtz(out2[2*kt  ][1][0], out2[2*kt  ][1][1]);
            u.p[2] = __builtin_amdgcn_cvt_pkrtz(out2[2*kt+1][0][0], out2[2*kt+1][0][1]);
            u.p[3] = __builtin_amdgcn_cvt_pkrtz(out2[2*kt+1][1][0], out2[2*kt+1][1][1]);
            bfrag[kt] = u.v;
        }
    };
    refresh();

    // ---------- persistent dt-scaled drift fragments + dt*bias ----------
    f16x8 aWd[4][2];
    #pragma unroll
    for (int Mt = 0; Mt < 4; ++Mt)
        #pragma unroll
        for (int kt = 0; kt < 2; ++kt)
            aWd[Mt][kt] = *(const f16x8*)(wbuf + 4096 + (Mt * 2 + kt) * 512 + fbase);

    f32x4 biasd[4];
    #pragma unroll
    for (int Mt = 0; Mt < 4; ++Mt) {
        f32x4 b = *(const f32x4*)(b_drift + Mt * 16 + g * 4);
        biasd[Mt][0] = b[0] * dt; biasd[Mt][1] = b[1] * dt;
        biasd[Mt][2] = b[2] * dt; biasd[Mt][3] = b[3] * dt;
    }

    __syncthreads();   // all waves done reading wbuf phase A

    // ---------- stage W1^T fragments (14 frags, zero-padded, phase B) ----------
    for (int idx2 = tid; idx2 < 3584; idx2 += 256) {
        const int fi    = idx2 >> 8;           // fragment 0..13
        const int lane2 = (idx2 >> 2) & 63;
        const int j     = (idx2 & 3) * 2;
        const int n     = (fi >> 1) * 16 + (lane2 & 15);
        const int k     = (fi & 1) * 32 + ((j & 4) ? 16 : 0)
                        + (lane2 >> 4) * 4 + (j & 3);
        const float v0 = (n < HID) ? W1[k * HID + n] : 0.0f;
        const float v1 = (n < HID) ? W1[(k + 1) * HID + n] : 0.0f;
        *(h2*)(wbuf + idx2 * 2) = __builtin_amdgcn_cvt_pkrtz(v0, v1);
    }
    __syncthreads();

    // ---------- head on initial state: logit = relu(out0@W1+b1)@W2 + b2 ----------
    float partial = 0.0f;
    #pragma unroll
    for (int Mt = 0; Mt < 7; ++Mt) {          // HID padded 100 -> 112
        f32x4 acc;
        #pragma unroll
        for (int reg = 0; reg < 4; ++reg) {
            const int n = Mt * 16 + g * 4 + reg;
            acc[reg] = (n < HID) ? b1[n] : 0.0f;
        }
        #pragma unroll
        for (int kt = 0; kt < 2; ++kt)
            acc = __builtin_amdgcn_mfma_f32_16x16x32_f16(
                *(const f16x8*)(wbuf + (Mt * 2 + kt) * 512 + fbase),
                bfrag[kt], acc, 0, 0, 0);
        #pragma unroll
        for (int reg = 0; reg < 4; ++reg) {
            const int n = Mt * 16 + g * 4 + reg;
            if (n < HID) partial += fmaxf(acc[reg], 0.0f) * W2[n];
        }
    }
    partial += __shfl_xor(partial, 16);
    partial += __shfl_xor(partial, 32);
    const float logit = partial + b2[0];
    const float scale = 0.5f * (1.0f / (1.0f + expf(-logit)))
                      * powf(0.04f, 1.0f / 1.8f);
    const f32x2 scale2 = { scale, scale };
    const f32x2 c104   = { 1.04f, 1.04f };
    const f32x2 zero2  = { 0.0f, 0.0f };

    // ---------- 25 SDE steps, all in registers ----------
    for (int t = 0; t < DEPTH; ++t) {
        // noise reads are same-address broadcasts within each 16-lane group
        f32x4 nz[4];
        #pragma unroll
        for (int Mt = 0; Mt < 4; ++Mt)
            nz[Mt] = *(const f32x4*)(noise_lds + t * DIM + Mt * 16 + g * 4);

        f32x4 acc[4];
        #pragma unroll
        for (int Mt = 0; Mt < 4; ++Mt) {
            acc[Mt] = __builtin_amdgcn_mfma_f32_16x16x32_f16(
                aWd[Mt][0], bfrag[0], biasd[Mt], 0, 0, 0);
            acc[Mt] = __builtin_amdgcn_mfma_f32_16x16x32_f16(
                aWd[Mt][1], bfrag[1], acc[Mt], 0, 0, 0);
        }
        // out = fma(scale, nz, fma(out, 1.04, relu(acc_dt_scaled)))  [packed f32]
        #pragma unroll
        for (int Mt = 0; Mt < 4; ++Mt) {
            #pragma unroll
            for (int h = 0; h < 2; ++h) {
                f32x2 a2 = { acc[Mt][2*h], acc[Mt][2*h+1] };
                f32x2 n2 = { nz[Mt][2*h],  nz[Mt][2*h+1] };
                f32x2 rel = __builtin_elementwise_max(a2, zero2);
                f32x2 tmp = __builtin_elementwise_fma(out2[Mt][h], c104, rel);
                out2[Mt][h] = __builtin_elementwise_fma(scale2, n2, tmp);
            }
        }
        refresh();
    }

    // ---- final drift (undo dt scaling: relu(z) = relu(dt*z)*25) + stores ----
    const long long out2_off = (long long)batch * DIM;
    #pragma unroll
    for (int Mt = 0; Mt < 4; ++Mt) {
        f32x4 acc = __builtin_amdgcn_mfma_f32_16x16x32_f16(
            aWd[Mt][0], bfrag[0], biasd[Mt], 0, 0, 0);
        acc = __builtin_amdgcn_mfma_f32_16x16x32_f16(
            aWd[Mt][1], bfrag[1], acc, 0, 0, 0);
        float o0 = out2[Mt][0][0], o1 = out2[Mt][0][1];
        float o2 = out2[Mt][1][0], o3 = out2[Mt][1][1];
        float4 dv, ov;
        dv.x = fmaf(fmaxf(acc[0], 0.0f), 25.0f, o0);
        dv.y = fmaf(fmaxf(acc[1], 0.0f), 25.0f, o1);
        dv.z = fmaf(fmaxf(acc[2], 0.0f), 25.0f, o2);
        dv.w = fmaf(fmaxf(acc[3], 0.0f), 25.0f, o3);
        ov.x = o0; ov.y = o1; ov.z = o2; ov.w = o3;
        *(float4*)(out + (long long)row * DIM + Mt * 16 + g * 4) = dv;
        *(float4*)(out + out2_off + (long long)row * DIM + Mt * 16 + g * 4) = ov;
    }
}

extern "C" void kernel_launch(void* const* d_in, const int* in_sizes, int n_in,
                              void* d_out, int out_size, void* d_ws, size_t ws_size,
                              hipStream_t stream) {
    const float* x       = (const float*)d_in[0];
    const float* u_raw   = (const float*)d_in[1];
    const float* w_raw   = (const float*)d_in[2];
    const float* W_down  = (const float*)d_in[3];
    const float* b_down  = (const float*)d_in[4];
    const float* W_drift = (const float*)d_in[5];
    const float* b_drift = (const float*)d_in[6];
    const float* W1      = (const float*)d_in[7];
    const float* b1      = (const float*)d_in[8];
    const float* W2      = (const float*)d_in[9];
    const float* b2      = (const float*)d_in[10];
    float* out   = (float*)d_out;
    float* noise = (float*)d_ws;               // 1600 floats scratch

    const int batch = in_sizes[0] / DIM;       // 262144
    const int blocks = batch / 64;

    levy_noise_kernel<<<DEPTH, 64, 0, stream>>>(u_raw, w_raw, noise);
    sdenet_fused<<<blocks, 256, 0, stream>>>(
        x, noise, W_down, b_down, W_drift, b_drift,
        W1, b1, W2, b2, out, batch);
}

// Round 4
// 269.463 us; speedup vs baseline: 1.3938x; 1.0694x over previous
//
#include <hip/hip_runtime.h>

#define DEPTH 25
#define DIM   64
#define HID   100

typedef _Float16 f16x4 __attribute__((ext_vector_type(4)));
typedef _Float16 f16x8 __attribute__((ext_vector_type(8)));
typedef __fp16   h2    __attribute__((ext_vector_type(2)));   // cvt_pkrtz result type
typedef float    f32x4 __attribute__((ext_vector_type(4)));
typedef float    f32x2 __attribute__((ext_vector_type(2)));

// ---- Pre-kernel: Levy noise (Chambers-Mallows-Stuck, alpha=1.8, beta=0) ----
__global__ __launch_bounds__(64) void levy_noise_kernel(
    const float* __restrict__ u_raw, const float* __restrict__ w_raw,
    float* __restrict__ noise)
{
    const int idx = blockIdx.x * 64 + threadIdx.x;
    if (idx >= DEPTH * DIM) return;
    float u = u_raw[idx];
    float w = w_raw[idx];
    float U  = 3.14159265358979323846f * (u - 0.5f);
    float Wv = -logf(fminf(fmaxf(w, 1e-12f), 1.0f));
    float t1 = sinf(1.8f * U) / powf(cosf(U), 0.5555555555555556f);
    float ratio = cosf(0.8f * U) / fmaxf(Wv, 1e-12f);
    float X = t1 * powf(ratio, -0.4444444444444444f);
    noise[idx] = fminf(fmaxf(0.1f * X, -10.0f), 10.0f);
}

union frag_u { h2 p[4]; f16x8 v; };

// One block = 256 threads = 4 waves; each wave owns 16 batch rows.
// State kept TRANSPOSED (out^T). mfma_f32_16x16x32_f16 stacked-halves K
// layout (VERIFIED round 2). Weights in LDS in FRAGMENT ORDER (conflict-free
// ds_read_b128, verified round 3: SQ_LDS_BANK_CONFLICT = 0).
//
// Round-4 changes (latency-bound diagnosis: all pipes <=20% busy, 3 waves/SIMD):
//  * __launch_bounds__(256,4): cap unified VGPR+AGPR at 128 -> 4 waves/SIMD.
//  * dt*b_drift accumulator-init moved to LDS (frees 16 persistent VGPRs).
//  * ALL staging (noise, bias, W_down, dt*W_drift, W1) before ONE barrier
//    (was 3 barriers with full vmcnt/lgkmcnt drains each).
//  * 25-step loop fully unrolled -> LDS offsets become immediates.
__global__ __launch_bounds__(256, 4) void sdenet_fused(
    const float* __restrict__ x,      const float* __restrict__ noise_g,
    const float* __restrict__ W_down, const float* __restrict__ b_down,
    const float* __restrict__ W_drift,const float* __restrict__ b_drift,
    const float* __restrict__ W1,     const float* __restrict__ b1,
    const float* __restrict__ W2,     const float* __restrict__ b2,
    float* __restrict__ out, int batch)
{
    __shared__ float    noise_lds[DEPTH * DIM];   // 6400 B
    __shared__ float    bias_lds[DIM];            // 256 B  (dt * b_drift)
    __shared__ _Float16 wdown[4096];              // 8 frags  (fi = Mt*2+kt)
    __shared__ _Float16 wdrift[4096];             // 8 frags, dt-scaled
    __shared__ _Float16 w1buf[7168];              // 14 frags, zero-padded n>=100

    const int tid  = threadIdx.x;
    const int wave = tid >> 6;
    const int lane = tid & 63;
    const int r    = lane & 15;        // batch row within wave tile (B/C col)
    const int g    = lane >> 4;        // 16-lane group 0..3
    const int row  = blockIdx.x * 64 + wave * 16 + r;
    const int fbase = lane * 8;        // per-lane fragment offset (halves)
    const float dt = 0.04f;

    // ---------- stage EVERYTHING, single barrier ----------
    {
        const float4* src = (const float4*)noise_g;
        float4* dst = (float4*)noise_lds;
        #pragma unroll
        for (int it = 0; it < 2; ++it) {
            int idx = tid + it * 256;
            if (idx < DEPTH * DIM / 4) dst[idx] = src[idx];
        }
    }
    if (tid < DIM) bias_lds[tid] = dt * b_drift[tid];

    // W_down / dt*W_drift fragments (8 each; idx2 indexes h2 pairs)
    for (int idx2 = tid; idx2 < 2048; idx2 += 256) {
        const int fi    = idx2 >> 8;           // fragment 0..7
        const int lane2 = (idx2 >> 2) & 63;
        const int j     = (idx2 & 3) * 2;      // elem pair start 0,2,4,6
        const int m     = (fi >> 1) * 16 + (lane2 & 15);
        const int k     = (fi & 1) * 32 + ((j & 4) ? 16 : 0)
                        + (lane2 >> 4) * 4 + (j & 3);
        *(h2*)(wdown + idx2 * 2) =
            __builtin_amdgcn_cvt_pkrtz(W_down[k * DIM + m],
                                       W_down[(k + 1) * DIM + m]);
        *(h2*)(wdrift + idx2 * 2) =
            __builtin_amdgcn_cvt_pkrtz(dt * W_drift[k * DIM + m],
                                       dt * W_drift[(k + 1) * DIM + m]);
    }
    // W1 fragments (14, zero-padded)
    for (int idx2 = tid; idx2 < 3584; idx2 += 256) {
        const int fi    = idx2 >> 8;           // fragment 0..13
        const int lane2 = (idx2 >> 2) & 63;
        const int j     = (idx2 & 3) * 2;
        const int n     = (fi >> 1) * 16 + (lane2 & 15);
        const int k     = (fi & 1) * 32 + ((j & 4) ? 16 : 0)
                        + (lane2 >> 4) * 4 + (j & 3);
        const float v0 = (n < HID) ? W1[k * HID + n] : 0.0f;
        const float v1 = (n < HID) ? W1[(k + 1) * HID + n] : 0.0f;
        *(h2*)(w1buf + idx2 * 2) = __builtin_amdgcn_cvt_pkrtz(v0, v1);
    }

    // prefetch x (global latency overlaps staging drain)
    float4 xlo[2], xhi[2];
    #pragma unroll
    for (int kt = 0; kt < 2; ++kt) {
        xlo[kt] = *(const float4*)(x + row * DIM + kt * 32 + g * 4);
        xhi[kt] = *(const float4*)(x + row * DIM + kt * 32 + 16 + g * 4);
    }
    __syncthreads();   // the ONLY barrier

    // ---------- initial: out0^T = W_down^T @ x^T + b_down ----------
    f16x8 bfrag[2];
    #pragma unroll
    for (int kt = 0; kt < 2; ++kt) {
        frag_u u;
        u.p[0] = __builtin_amdgcn_cvt_pkrtz(xlo[kt].x, xlo[kt].y);
        u.p[1] = __builtin_amdgcn_cvt_pkrtz(xlo[kt].z, xlo[kt].w);
        u.p[2] = __builtin_amdgcn_cvt_pkrtz(xhi[kt].x, xhi[kt].y);
        u.p[3] = __builtin_amdgcn_cvt_pkrtz(xhi[kt].z, xhi[kt].w);
        bfrag[kt] = u.v;
    }

    f32x2 out2[4][2];   // master fp32 state, C/D layout (dim = Mt*16 + 4g + reg)
    #pragma unroll
    for (int Mt = 0; Mt < 4; ++Mt) {
        f32x4 acc = *(const f32x4*)(b_down + Mt * 16 + g * 4);
        #pragma unroll
        for (int kt = 0; kt < 2; ++kt)
            acc = __builtin_amdgcn_mfma_f32_16x16x32_f16(
                *(const f16x8*)(wdown + (Mt * 2 + kt) * 512 + fbase),
                bfrag[kt], acc, 0, 0, 0);
        out2[Mt][0][0] = acc[0]; out2[Mt][0][1] = acc[1];
        out2[Mt][1][0] = acc[2]; out2[Mt][1][1] = acc[3];
    }

    // refresh B fragments from state: 8 packed RTZ converts
    auto refresh = [&]() {
        #pragma unroll
        for (int kt = 0; kt < 2; ++kt) {
            frag_u u;
            u.p[0] = __builtin_amdgcn_cvt_pkrtz(out2[2*kt  ][0][0], out2[2*kt  ][0][1]);
            u.p[1] = __builtin_amdgcn_cvt_pkrtz(out2[2*kt  ][1][0], out2[2*kt  ][1][1]);
            u.p[2] = __builtin_amdgcn_cvt_pkrtz(out2[2*kt+1][0][0], out2[2*kt+1][0][1]);
            u.p[3] = __builtin_amdgcn_cvt_pkrtz(out2[2*kt+1][1][0], out2[2*kt+1][1][1]);
            bfrag[kt] = u.v;
        }
    };
    refresh();

    // ---------- head on initial state: logit = relu(out0@W1+b1)@W2 + b2 ----------
    float partial = 0.0f;
    #pragma unroll
    for (int Mt = 0; Mt < 7; ++Mt) {          // HID padded 100 -> 112
        f32x4 acc;
        #pragma unroll
        for (int reg = 0; reg < 4; ++reg) {
            const int n = Mt * 16 + g * 4 + reg;
            acc[reg] = (n < HID) ? b1[n] : 0.0f;
        }
        #pragma unroll
        for (int kt = 0; kt < 2; ++kt)
            acc = __builtin_amdgcn_mfma_f32_16x16x32_f16(
                *(const f16x8*)(w1buf + (Mt * 2 + kt) * 512 + fbase),
                bfrag[kt], acc, 0, 0, 0);
        #pragma unroll
        for (int reg = 0; reg < 4; ++reg) {
            const int n = Mt * 16 + g * 4 + reg;
            if (n < HID) partial += fmaxf(acc[reg], 0.0f) * W2[n];
        }
    }
    partial += __shfl_xor(partial, 16);
    partial += __shfl_xor(partial, 32);
    const float logit = partial + b2[0];
    const float scale = 0.5f * (1.0f / (1.0f + expf(-logit)))
                      * powf(0.04f, 1.0f / 1.8f);
    const f32x2 scale2 = { scale, scale };
    const f32x2 c104   = { 1.04f, 1.04f };
    const f32x2 zero2  = { 0.0f, 0.0f };

    // ---------- persistent dt-scaled drift fragments ----------
    f16x8 aWd[4][2];
    #pragma unroll
    for (int Mt = 0; Mt < 4; ++Mt)
        #pragma unroll
        for (int kt = 0; kt < 2; ++kt)
            aWd[Mt][kt] = *(const f16x8*)(wdrift + (Mt * 2 + kt) * 512 + fbase);

    // ---------- 25 SDE steps, all in registers ----------
    #pragma unroll
    for (int t = 0; t < DEPTH; ++t) {
        // same-address broadcasts within each 16-lane group; immediate offsets
        f32x4 nz[4];
        #pragma unroll
        for (int Mt = 0; Mt < 4; ++Mt)
            nz[Mt] = *(const f32x4*)(noise_lds + t * DIM + Mt * 16 + g * 4);

        f32x4 acc[4];
        #pragma unroll
        for (int Mt = 0; Mt < 4; ++Mt) {
            acc[Mt] = *(const f32x4*)(bias_lds + Mt * 16 + g * 4);  // dt*b_drift
            acc[Mt] = __builtin_amdgcn_mfma_f32_16x16x32_f16(
                aWd[Mt][0], bfrag[0], acc[Mt], 0, 0, 0);
            acc[Mt] = __builtin_amdgcn_mfma_f32_16x16x32_f16(
                aWd[Mt][1], bfrag[1], acc[Mt], 0, 0, 0);
        }
        // out = fma(scale, nz, fma(out, 1.04, relu(acc_dt_scaled)))  [packed f32]
        #pragma unroll
        for (int Mt = 0; Mt < 4; ++Mt) {
            #pragma unroll
            for (int h = 0; h < 2; ++h) {
                f32x2 a2 = { acc[Mt][2*h], acc[Mt][2*h+1] };
                f32x2 n2 = { nz[Mt][2*h],  nz[Mt][2*h+1] };
                f32x2 rel = __builtin_elementwise_max(a2, zero2);
                f32x2 tmp = __builtin_elementwise_fma(out2[Mt][h], c104, rel);
                out2[Mt][h] = __builtin_elementwise_fma(scale2, n2, tmp);
            }
        }
        refresh();
    }

    // ---- final drift (undo dt scaling: relu(z) = relu(dt*z)*25) + stores ----
    const long long out2_off = (long long)batch * DIM;
    #pragma unroll
    for (int Mt = 0; Mt < 4; ++Mt) {
        f32x4 acc = *(const f32x4*)(bias_lds + Mt * 16 + g * 4);
        acc = __builtin_amdgcn_mfma_f32_16x16x32_f16(
            aWd[Mt][0], bfrag[0], acc, 0, 0, 0);
        acc = __builtin_amdgcn_mfma_f32_16x16x32_f16(
            aWd[Mt][1], bfrag[1], acc, 0, 0, 0);
        float o0 = out2[Mt][0][0], o1 = out2[Mt][0][1];
        float o2 = out2[Mt][1][0], o3 = out2[Mt][1][1];
        float4 dv, ov;
        dv.x = fmaf(fmaxf(acc[0], 0.0f), 25.0f, o0);
        dv.y = fmaf(fmaxf(acc[1], 0.0f), 25.0f, o1);
        dv.z = fmaf(fmaxf(acc[2], 0.0f), 25.0f, o2);
        dv.w = fmaf(fmaxf(acc[3], 0.0f), 25.0f, o3);
        ov.x = o0; ov.y = o1; ov.z = o2; ov.w = o3;
        *(float4*)(out + (long long)row * DIM + Mt * 16 + g * 4) = dv;
        *(float4*)(out + out2_off + (long long)row * DIM + Mt * 16 + g * 4) = ov;
    }
}

extern "C" void kernel_launch(void* const* d_in, const int* in_sizes, int n_in,
                              void* d_out, int out_size, void* d_ws, size_t ws_size,
                              hipStream_t stream) {
    const float* x       = (const float*)d_in[0];
    const float* u_raw   = (const float*)d_in[1];
    const float* w_raw   = (const float*)d_in[2];
    const float* W_down  = (const float*)d_in[3];
    const float* b_down  = (const float*)d_in[4];
    const float* W_drift = (const float*)d_in[5];
    const float* b_drift = (const float*)d_in[6];
    const float* W1      = (const float*)d_in[7];
    const float* b1      = (const float*)d_in[8];
    const float* W2      = (const float*)d_in[9];
    const float* b2      = (const float*)d_in[10];
    float* out   = (float*)d_out;
    float* noise = (float*)d_ws;               // 1600 floats scratch

    const int batch = in_sizes[0] / DIM;       // 262144
    const int blocks = batch / 64;

    levy_noise_kernel<<<DEPTH, 64, 0, stream>>>(u_raw, w_raw, noise);
    sdenet_fused<<<blocks, 256, 0, stream>>>(
        x, noise, W_down, b_down, W_drift, b_drift,
        W1, b1, W2, b2, out, batch);
}

// Round 5
// 245.693 us; speedup vs baseline: 1.5286x; 1.0967x over previous
//
#include <hip/hip_runtime.h>

#define DEPTH 25
#define DIM   64
#define HID   100

typedef _Float16 f16x4 __attribute__((ext_vector_type(4)));
typedef _Float16 f16x8 __attribute__((ext_vector_type(8)));
typedef __fp16   h2    __attribute__((ext_vector_type(2)));   // cvt_pkrtz result type
typedef float    f32x4 __attribute__((ext_vector_type(4)));
typedef float    f32x2 __attribute__((ext_vector_type(2)));

// ---- Pre-kernel: Levy noise (Chambers-Mallows-Stuck, alpha=1.8, beta=0) ----
__global__ __launch_bounds__(64) void levy_noise_kernel(
    const float* __restrict__ u_raw, const float* __restrict__ w_raw,
    float* __restrict__ noise)
{
    const int idx = blockIdx.x * 64 + threadIdx.x;
    if (idx >= DEPTH * DIM) return;
    float u = u_raw[idx];
    float w = w_raw[idx];
    float U  = 3.14159265358979323846f * (u - 0.5f);
    float Wv = -logf(fminf(fmaxf(w, 1e-12f), 1.0f));
    float t1 = sinf(1.8f * U) / powf(cosf(U), 0.5555555555555556f);
    float ratio = cosf(0.8f * U) / fmaxf(Wv, 1e-12f);
    float X = t1 * powf(ratio, -0.4444444444444444f);
    noise[idx] = fminf(fmaxf(0.1f * X, -10.0f), 10.0f);
}

// ---- Pre-kernel: convert weights to fragment-ordered f16, ONCE ----
// wpre halves: [0,4096) W_down frags | [4096,8192) dt*W_drift frags |
//              [8192,15360) W1 frags (n>=100 zero-padded).
// Fragment fi: lane l holds halves [fi*512 + l*8, +8) -> one ds-free,
// conflict-free, coalesced global_load_dwordx4 per MFMA operand.
__global__ __launch_bounds__(256) void preconv_kernel(
    const float* __restrict__ W_down, const float* __restrict__ W_drift,
    const float* __restrict__ W1,     const float* __restrict__ b1,
    const float* __restrict__ W2,
    _Float16* __restrict__ wpre, float* __restrict__ b1p, float* __restrict__ w2p)
{
    const int idx = blockIdx.x * 256 + threadIdx.x;   // h2-pair index
    if (idx < 7680) {
        int rel, kind;
        if (idx < 2048)      { kind = 0; rel = idx; }
        else if (idx < 4096) { kind = 1; rel = idx - 2048; }
        else                 { kind = 2; rel = idx - 4096; }
        const int fi    = rel >> 8;
        const int lane2 = (rel >> 2) & 63;
        const int j     = (rel & 3) * 2;
        const int m     = (fi >> 1) * 16 + (lane2 & 15);
        const int k     = (fi & 1) * 32 + ((j & 4) ? 16 : 0)
                        + (lane2 >> 4) * 4 + (j & 3);
        float v0, v1;
        if (kind == 0) {
            v0 = W_down[k * DIM + m];           v1 = W_down[(k + 1) * DIM + m];
        } else if (kind == 1) {
            v0 = 0.04f * W_drift[k * DIM + m];  v1 = 0.04f * W_drift[(k + 1) * DIM + m];
        } else {
            v0 = (m < HID) ? W1[k * HID + m] : 0.0f;
            v1 = (m < HID) ? W1[(k + 1) * HID + m] : 0.0f;
        }
        *(h2*)(wpre + idx * 2) = __builtin_amdgcn_cvt_pkrtz(v0, v1);
    } else if (idx < 7792) {
        const int i = idx - 7680;
        b1p[i] = (i < HID) ? b1[i] : 0.0f;      // padded to 112
    } else if (idx < 7904) {
        const int i = idx - 7792;
        w2p[i] = (i < HID) ? W2[i] : 0.0f;      // padded to 112
    }
}

union frag_u { h2 p[4]; f16x8 v; };

// ======================= PRE path (weights preconverted) =======================
// One block = 256 threads = 4 waves; each wave owns 16 batch rows.
// State kept TRANSPOSED (out^T). mfma_f32_16x16x32_f16 stacked-halves K layout
// (VERIFIED round 2). LDS = noise only (6.4 KB); weights read straight from
// the preconverted global buffer (L2-resident); dt*b_drift bias in registers.
__global__ __launch_bounds__(256, 4) void sdenet_fused_pre(
    const float* __restrict__ x,      const float* __restrict__ noise_g,
    const _Float16* __restrict__ wpre,
    const float* __restrict__ b_down, const float* __restrict__ b_drift,
    const float* __restrict__ b1p,    const float* __restrict__ w2p,
    const float* __restrict__ b2,
    float* __restrict__ out, int batch)
{
    __shared__ float noise_lds[DEPTH * DIM];   // 6400 B (the ONLY LDS)

    const int tid  = threadIdx.x;
    const int wave = tid >> 6;
    const int lane = tid & 63;
    const int r    = lane & 15;        // batch row within wave tile (B/C col)
    const int g    = lane >> 4;        // 16-lane group 0..3
    const int row  = blockIdx.x * 64 + wave * 16 + r;
    const int fbase = lane * 8;        // per-lane fragment offset (halves)
    const float dt = 0.04f;

    // noise -> LDS (400 float4s)
    {
        const float4* src = (const float4*)noise_g;
        float4* dst = (float4*)noise_lds;
        dst[tid] = src[tid];
        if (tid < 144) dst[tid + 256] = src[tid + 256];
    }
    // prefetch x (overlaps the LDS-write drain)
    float4 xlo[2], xhi[2];
    #pragma unroll
    for (int kt = 0; kt < 2; ++kt) {
        xlo[kt] = *(const float4*)(x + row * DIM + kt * 32 + g * 4);
        xhi[kt] = *(const float4*)(x + row * DIM + kt * 32 + 16 + g * 4);
    }
    __syncthreads();

    // ---------- initial: out0^T = W_down^T @ x^T + b_down ----------
    f16x8 bfrag[2];
    #pragma unroll
    for (int kt = 0; kt < 2; ++kt) {
        frag_u u;
        u.p[0] = __builtin_amdgcn_cvt_pkrtz(xlo[kt].x, xlo[kt].y);
        u.p[1] = __builtin_amdgcn_cvt_pkrtz(xlo[kt].z, xlo[kt].w);
        u.p[2] = __builtin_amdgcn_cvt_pkrtz(xhi[kt].x, xhi[kt].y);
        u.p[3] = __builtin_amdgcn_cvt_pkrtz(xhi[kt].z, xhi[kt].w);
        bfrag[kt] = u.v;
    }

    f32x2 out2[4][2];   // master fp32 state, C/D layout (dim = Mt*16 + 4g + reg)
    #pragma unroll
    for (int Mt = 0; Mt < 4; ++Mt) {
        f32x4 acc = *(const f32x4*)(b_down + Mt * 16 + g * 4);
        #pragma unroll
        for (int kt = 0; kt < 2; ++kt)
            acc = __builtin_amdgcn_mfma_f32_16x16x32_f16(
                *(const f16x8*)(wpre + (Mt * 2 + kt) * 512 + fbase),
                bfrag[kt], acc, 0, 0, 0);
        out2[Mt][0][0] = acc[0]; out2[Mt][0][1] = acc[1];
        out2[Mt][1][0] = acc[2]; out2[Mt][1][1] = acc[3];
    }

    // refresh B fragments from state: 8 packed RTZ converts
    auto refresh = [&]() {
        #pragma unroll
        for (int kt = 0; kt < 2; ++kt) {
            frag_u u;
            u.p[0] = __builtin_amdgcn_cvt_pkrtz(out2[2*kt  ][0][0], out2[2*kt  ][0][1]);
            u.p[1] = __builtin_amdgcn_cvt_pkrtz(out2[2*kt  ][1][0], out2[2*kt  ][1][1]);
            u.p[2] = __builtin_amdgcn_cvt_pkrtz(out2[2*kt+1][0][0], out2[2*kt+1][0][1]);
            u.p[3] = __builtin_amdgcn_cvt_pkrtz(out2[2*kt+1][1][0], out2[2*kt+1][1][1]);
            bfrag[kt] = u.v;
        }
    };
    refresh();

    // ---------- head: logit = relu(out0@W1+b1)@W2 + b2 (padded, no masks) ----------
    const _Float16* w1pre = wpre + 8192;
    float partial = 0.0f;
    #pragma unroll
    for (int Mt = 0; Mt < 7; ++Mt) {          // HID padded 100 -> 112
        f32x4 acc = *(const f32x4*)(b1p + Mt * 16 + g * 4);
        #pragma unroll
        for (int kt = 0; kt < 2; ++kt)
            acc = __builtin_amdgcn_mfma_f32_16x16x32_f16(
                *(const f16x8*)(w1pre + (Mt * 2 + kt) * 512 + fbase),
                bfrag[kt], acc, 0, 0, 0);
        #pragma unroll
        for (int reg = 0; reg < 4; ++reg)
            partial += fmaxf(acc[reg], 0.0f) * w2p[Mt * 16 + g * 4 + reg];
    }
    partial += __shfl_xor(partial, 16);
    partial += __shfl_xor(partial, 32);
    const float logit = partial + b2[0];
    const float scale = 0.5f * (1.0f / (1.0f + expf(-logit)))
                      * powf(0.04f, 1.0f / 1.8f);
    const f32x2 scale2 = { scale, scale };
    const f32x2 c104   = { 1.04f, 1.04f };
    const f32x2 zero2  = { 0.0f, 0.0f };

    // ---------- persistent dt-scaled drift fragments + dt*bias (registers) ----------
    f16x8 aWd[4][2];
    #pragma unroll
    for (int Mt = 0; Mt < 4; ++Mt)
        #pragma unroll
        for (int kt = 0; kt < 2; ++kt)
            aWd[Mt][kt] = *(const f16x8*)(wpre + 4096 + (Mt * 2 + kt) * 512 + fbase);

    f32x4 biasd[4];
    #pragma unroll
    for (int Mt = 0; Mt < 4; ++Mt) {
        f32x4 b = *(const f32x4*)(b_drift + Mt * 16 + g * 4);
        biasd[Mt][0] = b[0] * dt; biasd[Mt][1] = b[1] * dt;
        biasd[Mt][2] = b[2] * dt; biasd[Mt][3] = b[3] * dt;
    }

    // ---------- 25 SDE steps, all in registers ----------
    #pragma unroll
    for (int t = 0; t < DEPTH; ++t) {
        f32x4 nz[4];   // same-address broadcasts within each 16-lane group
        #pragma unroll
        for (int Mt = 0; Mt < 4; ++Mt)
            nz[Mt] = *(const f32x4*)(noise_lds + t * DIM + Mt * 16 + g * 4);

        f32x4 acc[4];
        #pragma unroll
        for (int Mt = 0; Mt < 4; ++Mt) {
            acc[Mt] = __builtin_amdgcn_mfma_f32_16x16x32_f16(
                aWd[Mt][0], bfrag[0], biasd[Mt], 0, 0, 0);
            acc[Mt] = __builtin_amdgcn_mfma_f32_16x16x32_f16(
                aWd[Mt][1], bfrag[1], acc[Mt], 0, 0, 0);
        }
        // out = fma(scale, nz, fma(out, 1.04, relu(acc_dt_scaled)))  [packed f32]
        #pragma unroll
        for (int Mt = 0; Mt < 4; ++Mt) {
            #pragma unroll
            for (int h = 0; h < 2; ++h) {
                f32x2 a2 = { acc[Mt][2*h], acc[Mt][2*h+1] };
                f32x2 n2 = { nz[Mt][2*h],  nz[Mt][2*h+1] };
                f32x2 rel = __builtin_elementwise_max(a2, zero2);
                f32x2 tmp = __builtin_elementwise_fma(out2[Mt][h], c104, rel);
                out2[Mt][h] = __builtin_elementwise_fma(scale2, n2, tmp);
            }
        }
        refresh();
    }

    // ---- final drift (undo dt scaling: relu(z) = relu(dt*z)*25) + stores ----
    const long long out2_off = (long long)batch * DIM;
    #pragma unroll
    for (int Mt = 0; Mt < 4; ++Mt) {
        f32x4 acc = __builtin_amdgcn_mfma_f32_16x16x32_f16(
            aWd[Mt][0], bfrag[0], biasd[Mt], 0, 0, 0);
        acc = __builtin_amdgcn_mfma_f32_16x16x32_f16(
            aWd[Mt][1], bfrag[1], acc, 0, 0, 0);
        float o0 = out2[Mt][0][0], o1 = out2[Mt][0][1];
        float o2 = out2[Mt][1][0], o3 = out2[Mt][1][1];
        float4 dv, ov;
        dv.x = fmaf(fmaxf(acc[0], 0.0f), 25.0f, o0);
        dv.y = fmaf(fmaxf(acc[1], 0.0f), 25.0f, o1);
        dv.z = fmaf(fmaxf(acc[2], 0.0f), 25.0f, o2);
        dv.w = fmaf(fmaxf(acc[3], 0.0f), 25.0f, o3);
        ov.x = o0; ov.y = o1; ov.z = o2; ov.w = o3;
        *(float4*)(out + (long long)row * DIM + Mt * 16 + g * 4) = dv;
        *(float4*)(out + out2_off + (long long)row * DIM + Mt * 16 + g * 4) = ov;
    }
}

// ============== FALLBACK path (round-4 kernel, in-block staging) ==============
__global__ __launch_bounds__(256, 4) void sdenet_fused_fb(
    const float* __restrict__ x,      const float* __restrict__ noise_g,
    const float* __restrict__ W_down, const float* __restrict__ b_down,
    const float* __restrict__ W_drift,const float* __restrict__ b_drift,
    const float* __restrict__ W1,     const float* __restrict__ b1,
    const float* __restrict__ W2,     const float* __restrict__ b2,
    float* __restrict__ out, int batch)
{
    __shared__ float    noise_lds[DEPTH * DIM];
    __shared__ float    bias_lds[DIM];
    __shared__ _Float16 wdown[4096];
    __shared__ _Float16 wdrift[4096];
    __shared__ _Float16 w1buf[7168];

    const int tid  = threadIdx.x;
    const int wave = tid >> 6;
    const int lane = tid & 63;
    const int r    = lane & 15;
    const int g    = lane >> 4;
    const int row  = blockIdx.x * 64 + wave * 16 + r;
    const int fbase = lane * 8;
    const float dt = 0.04f;

    {
        const float4* src = (const float4*)noise_g;
        float4* dst = (float4*)noise_lds;
        #pragma unroll
        for (int it = 0; it < 2; ++it) {
            int idx = tid + it * 256;
            if (idx < DEPTH * DIM / 4) dst[idx] = src[idx];
        }
    }
    if (tid < DIM) bias_lds[tid] = dt * b_drift[tid];

    for (int idx2 = tid; idx2 < 2048; idx2 += 256) {
        const int fi    = idx2 >> 8;
        const int lane2 = (idx2 >> 2) & 63;
        const int j     = (idx2 & 3) * 2;
        const int m     = (fi >> 1) * 16 + (lane2 & 15);
        const int k     = (fi & 1) * 32 + ((j & 4) ? 16 : 0)
                        + (lane2 >> 4) * 4 + (j & 3);
        *(h2*)(wdown + idx2 * 2) =
            __builtin_amdgcn_cvt_pkrtz(W_down[k * DIM + m],
                                       W_down[(k + 1) * DIM + m]);
        *(h2*)(wdrift + idx2 * 2) =
            __builtin_amdgcn_cvt_pkrtz(dt * W_drift[k * DIM + m],
                                       dt * W_drift[(k + 1) * DIM + m]);
    }
    for (int idx2 = tid; idx2 < 3584; idx2 += 256) {
        const int fi    = idx2 >> 8;
        const int lane2 = (idx2 >> 2) & 63;
        const int j     = (idx2 & 3) * 2;
        const int n     = (fi >> 1) * 16 + (lane2 & 15);
        const int k     = (fi & 1) * 32 + ((j & 4) ? 16 : 0)
                        + (lane2 >> 4) * 4 + (j & 3);
        const float v0 = (n < HID) ? W1[k * HID + n] : 0.0f;
        const float v1 = (n < HID) ? W1[(k + 1) * HID + n] : 0.0f;
        *(h2*)(w1buf + idx2 * 2) = __builtin_amdgcn_cvt_pkrtz(v0, v1);
    }

    float4 xlo[2], xhi[2];
    #pragma unroll
    for (int kt = 0; kt < 2; ++kt) {
        xlo[kt] = *(const float4*)(x + row * DIM + kt * 32 + g * 4);
        xhi[kt] = *(const float4*)(x + row * DIM + kt * 32 + 16 + g * 4);
    }
    __syncthreads();

    f16x8 bfrag[2];
    #pragma unroll
    for (int kt = 0; kt < 2; ++kt) {
        frag_u u;
        u.p[0] = __builtin_amdgcn_cvt_pkrtz(xlo[kt].x, xlo[kt].y);
        u.p[1] = __builtin_amdgcn_cvt_pkrtz(xlo[kt].z, xlo[kt].w);
        u.p[2] = __builtin_amdgcn_cvt_pkrtz(xhi[kt].x, xhi[kt].y);
        u.p[3] = __builtin_amdgcn_cvt_pkrtz(xhi[kt].z, xhi[kt].w);
        bfrag[kt] = u.v;
    }

    f32x2 out2[4][2];
    #pragma unroll
    for (int Mt = 0; Mt < 4; ++Mt) {
        f32x4 acc = *(const f32x4*)(b_down + Mt * 16 + g * 4);
        #pragma unroll
        for (int kt = 0; kt < 2; ++kt)
            acc = __builtin_amdgcn_mfma_f32_16x16x32_f16(
                *(const f16x8*)(wdown + (Mt * 2 + kt) * 512 + fbase),
                bfrag[kt], acc, 0, 0, 0);
        out2[Mt][0][0] = acc[0]; out2[Mt][0][1] = acc[1];
        out2[Mt][1][0] = acc[2]; out2[Mt][1][1] = acc[3];
    }

    auto refresh = [&]() {
        #pragma unroll
        for (int kt = 0; kt < 2; ++kt) {
            frag_u u;
            u.p[0] = __builtin_amdgcn_cvt_pkrtz(out2[2*kt  ][0][0], out2[2*kt  ][0][1]);
            u.p[1] = __builtin_amdgcn_cvt_pkrtz(out2[2*kt  ][1][0], out2[2*kt  ][1][1]);
            u.p[2] = __builtin_amdgcn_cvt_pkrtz(out2[2*kt+1][0][0], out2[2*kt+1][0][1]);
            u.p[3] = __builtin_amdgcn_cvt_pkrtz(out2[2*kt+1][1][0], out2[2*kt+1][1][1]);
            bfrag[kt] = u.v;
        }
    };
    refresh();

    float partial = 0.0f;
    #pragma unroll
    for (int Mt = 0; Mt < 7; ++Mt) {
        f32x4 acc;
        #pragma unroll
        for (int reg = 0; reg < 4; ++reg) {
            const int n = Mt * 16 + g * 4 + reg;
            acc[reg] = (n < HID) ? b1[n] : 0.0f;
        }
        #pragma unroll
        for (int kt = 0; kt < 2; ++kt)
            acc = __builtin_amdgcn_mfma_f32_16x16x32_f16(
                *(const f16x8*)(w1buf + (Mt * 2 + kt) * 512 + fbase),
                bfrag[kt], acc, 0, 0, 0);
        #pragma unroll
        for (int reg = 0; reg < 4; ++reg) {
            const int n = Mt * 16 + g * 4 + reg;
            if (n < HID) partial += fmaxf(acc[reg], 0.0f) * W2[n];
        }
    }
    partial += __shfl_xor(partial, 16);
    partial += __shfl_xor(partial, 32);
    const float logit = partial + b2[0];
    const float scale = 0.5f * (1.0f / (1.0f + expf(-logit)))
                      * powf(0.04f, 1.0f / 1.8f);
    const f32x2 scale2 = { scale, scale };
    const f32x2 c104   = { 1.04f, 1.04f };
    const f32x2 zero2  = { 0.0f, 0.0f };

    f16x8 aWd[4][2];
    #pragma unroll
    for (int Mt = 0; Mt < 4; ++Mt)
        #pragma unroll
        for (int kt = 0; kt < 2; ++kt)
            aWd[Mt][kt] = *(const f16x8*)(wdrift + (Mt * 2 + kt) * 512 + fbase);

    #pragma unroll
    for (int t = 0; t < DEPTH; ++t) {
        f32x4 nz[4];
        #pragma unroll
        for (int Mt = 0; Mt < 4; ++Mt)
            nz[Mt] = *(const f32x4*)(noise_lds + t * DIM + Mt * 16 + g * 4);

        f32x4 acc[4];
        #pragma unroll
        for (int Mt = 0; Mt < 4; ++Mt) {
            acc[Mt] = *(const f32x4*)(bias_lds + Mt * 16 + g * 4);
            acc[Mt] = __builtin_amdgcn_mfma_f32_16x16x32_f16(
                aWd[Mt][0], bfrag[0], acc[Mt], 0, 0, 0);
            acc[Mt] = __builtin_amdgcn_mfma_f32_16x16x32_f16(
                aWd[Mt][1], bfrag[1], acc[Mt], 0, 0, 0);
        }
        #pragma unroll
        for (int Mt = 0; Mt < 4; ++Mt) {
            #pragma unroll
            for (int h = 0; h < 2; ++h) {
                f32x2 a2 = { acc[Mt][2*h], acc[Mt][2*h+1] };
                f32x2 n2 = { nz[Mt][2*h],  nz[Mt][2*h+1] };
                f32x2 rel = __builtin_elementwise_max(a2, zero2);
                f32x2 tmp = __builtin_elementwise_fma(out2[Mt][h], c104, rel);
                out2[Mt][h] = __builtin_elementwise_fma(scale2, n2, tmp);
            }
        }
        refresh();
    }

    const long long out2_off = (long long)batch * DIM;
    #pragma unroll
    for (int Mt = 0; Mt < 4; ++Mt) {
        f32x4 acc = *(const f32x4*)(bias_lds + Mt * 16 + g * 4);
        acc = __builtin_amdgcn_mfma_f32_16x16x32_f16(
            aWd[Mt][0], bfrag[0], acc, 0, 0, 0);
        acc = __builtin_amdgcn_mfma_f32_16x16x32_f16(
            aWd[Mt][1], bfrag[1], acc, 0, 0, 0);
        float o0 = out2[Mt][0][0], o1 = out2[Mt][0][1];
        float o2 = out2[Mt][1][0], o3 = out2[Mt][1][1];
        float4 dv, ov;
        dv.x = fmaf(fmaxf(acc[0], 0.0f), 25.0f, o0);
        dv.y = fmaf(fmaxf(acc[1], 0.0f), 25.0f, o1);
        dv.z = fmaf(fmaxf(acc[2], 0.0f), 25.0f, o2);
        dv.w = fmaf(fmaxf(acc[3], 0.0f), 25.0f, o3);
        ov.x = o0; ov.y = o1; ov.z = o2; ov.w = o3;
        *(float4*)(out + (long long)row * DIM + Mt * 16 + g * 4) = dv;
        *(float4*)(out + out2_off + (long long)row * DIM + Mt * 16 + g * 4) = ov;
    }
}

extern "C" void kernel_launch(void* const* d_in, const int* in_sizes, int n_in,
                              void* d_out, int out_size, void* d_ws, size_t ws_size,
                              hipStream_t stream) {
    const float* x       = (const float*)d_in[0];
    const float* u_raw   = (const float*)d_in[1];
    const float* w_raw   = (const float*)d_in[2];
    const float* W_down  = (const float*)d_in[3];
    const float* b_down  = (const float*)d_in[4];
    const float* W_drift = (const float*)d_in[5];
    const float* b_drift = (const float*)d_in[6];
    const float* W1      = (const float*)d_in[7];
    const float* b1      = (const float*)d_in[8];
    const float* W2      = (const float*)d_in[9];
    const float* b2      = (const float*)d_in[10];
    float* out   = (float*)d_out;

    // workspace layout: [0,6400) noise f32 | [6400,37120) wpre f16 |
    //                   [37120,37568) b1p  | [37568,38016) w2p
    float*     noise = (float*)d_ws;
    _Float16*  wpre  = (_Float16*)((char*)d_ws + 6400);
    float*     b1p   = (float*)((char*)d_ws + 37120);
    float*     w2p   = (float*)((char*)d_ws + 37568);

    const int batch = in_sizes[0] / DIM;       // 262144
    const int blocks = batch / 64;

    levy_noise_kernel<<<DEPTH, 64, 0, stream>>>(u_raw, w_raw, noise);

    if (ws_size >= 38016) {
        preconv_kernel<<<31, 256, 0, stream>>>(W_down, W_drift, W1, b1, W2,
                                               wpre, b1p, w2p);
        sdenet_fused_pre<<<blocks, 256, 0, stream>>>(
            x, noise, wpre, b_down, b_drift, b1p, w2p, b2, out, batch);
    } else {
        sdenet_fused_fb<<<blocks, 256, 0, stream>>>(
            x, noise, W_down, b_down, W_drift, b_drift,
            W1, b1, W2, b2, out, batch);
    }
}

// Round 6
// 241.267 us; speedup vs baseline: 1.5567x; 1.0183x over previous
//
#include <hip/hip_runtime.h>

#define DEPTH 25
#define DIM   64
#define HID   100

typedef _Float16 f16x4 __attribute__((ext_vector_type(4)));
typedef _Float16 f16x8 __attribute__((ext_vector_type(8)));
typedef __fp16   h2    __attribute__((ext_vector_type(2)));   // cvt_pkrtz result type
typedef float    f32x4 __attribute__((ext_vector_type(4)));
typedef float    f32x2 __attribute__((ext_vector_type(2)));

// ---- Prep kernel: Levy noise + fragment-ordered f16 weights, ONCE ----
// wpre halves: [0,4096) W_down frags | [4096,8192) dt*W_drift frags |
//              [8192,15360) W1 frags (n>=100 zero-padded).
// Fragment fi: lane l holds halves [fi*512 + l*8, +8).
__global__ __launch_bounds__(256) void prep_kernel(
    const float* __restrict__ u_raw,  const float* __restrict__ w_raw,
    const float* __restrict__ W_down, const float* __restrict__ W_drift,
    const float* __restrict__ W1,     const float* __restrict__ b1,
    const float* __restrict__ W2,
    float* __restrict__ noise, _Float16* __restrict__ wpre,
    float* __restrict__ b1p, float* __restrict__ w2p)
{
    const int idx = blockIdx.x * 256 + threadIdx.x;
    if (idx < DEPTH * DIM) {
        float u = u_raw[idx];
        float w = w_raw[idx];
        float U  = 3.14159265358979323846f * (u - 0.5f);
        float Wv = -logf(fminf(fmaxf(w, 1e-12f), 1.0f));
        float t1 = sinf(1.8f * U) / powf(cosf(U), 0.5555555555555556f);
        float ratio = cosf(0.8f * U) / fmaxf(Wv, 1e-12f);
        float X = t1 * powf(ratio, -0.4444444444444444f);
        noise[idx] = fminf(fmaxf(0.1f * X, -10.0f), 10.0f);
    } else if (idx < 1600 + 7680) {
        const int p = idx - 1600;              // h2-pair index
        int rel, kind;
        if (p < 2048)      { kind = 0; rel = p; }
        else if (p < 4096) { kind = 1; rel = p - 2048; }
        else               { kind = 2; rel = p - 4096; }
        const int fi    = rel >> 8;
        const int lane2 = (rel >> 2) & 63;
        const int j     = (rel & 3) * 2;
        const int m     = (fi >> 1) * 16 + (lane2 & 15);
        const int k     = (fi & 1) * 32 + ((j & 4) ? 16 : 0)
                        + (lane2 >> 4) * 4 + (j & 3);
        float v0, v1;
        if (kind == 0) {
            v0 = W_down[k * DIM + m];           v1 = W_down[(k + 1) * DIM + m];
        } else if (kind == 1) {
            v0 = 0.04f * W_drift[k * DIM + m];  v1 = 0.04f * W_drift[(k + 1) * DIM + m];
        } else {
            v0 = (m < HID) ? W1[k * HID + m] : 0.0f;
            v1 = (m < HID) ? W1[(k + 1) * HID + m] : 0.0f;
        }
        *(h2*)(wpre + p * 2) = __builtin_amdgcn_cvt_pkrtz(v0, v1);
    } else if (idx < 9280 + 112) {
        const int i = idx - 9280;
        b1p[i] = (i < HID) ? b1[i] : 0.0f;      // padded to 112
    } else if (idx < 9392 + 112) {
        const int i = idx - 9392;
        w2p[i] = (i < HID) ? W2[i] : 0.0f;      // padded to 112
    }
}

union frag_u { h2 p[4]; f16x8 v; };

// ===================== PRE path: 32 rows/wave, 2 chains =====================
// One block = 256 threads = 4 waves; each wave owns 32 batch rows as TWO
// independent 16-row chains (A,B). While chain A runs eltwise/cvt, chain B's
// MFMAs issue -> ~2x independent instruction streams per wave (the round-5
// diagnosis: 37 us of dependency bubbles at fixed work).
// mfma_f32_16x16x32_f16 stacked-halves K layout (VERIFIED round 2).
// nz ds_reads are SHARED by both chains (noise is row-independent).
__global__ __launch_bounds__(256, 3) void sdenet_fused_pre2(
    const float* __restrict__ x,      const float* __restrict__ noise_g,
    const _Float16* __restrict__ wpre,
    const float* __restrict__ b_down, const float* __restrict__ b_drift,
    const float* __restrict__ b1p,    const float* __restrict__ w2p,
    const float* __restrict__ b2,
    float* __restrict__ out, int batch)
{
    __shared__ float noise_lds[DEPTH * DIM];   // 6400 B (the ONLY LDS)

    const int tid  = threadIdx.x;
    const int wave = tid >> 6;
    const int lane = tid & 63;
    const int r    = lane & 15;        // batch row within chain (B/C col)
    const int g    = lane >> 4;        // 16-lane group 0..3
    const int base = blockIdx.x * 128 + wave * 32;
    const int rowA = base + r;
    const int rowB = base + 16 + r;
    const int fbase = lane * 8;        // per-lane fragment offset (halves)
    const float dt = 0.04f;

    // noise -> LDS (400 float4s)
    {
        const float4* src = (const float4*)noise_g;
        float4* dst = (float4*)noise_lds;
        dst[tid] = src[tid];
        if (tid < 144) dst[tid + 256] = src[tid + 256];
    }
    // prefetch x for both chains (overlaps the LDS-write drain)
    float4 xA[4], xB[4];
    #pragma unroll
    for (int kt = 0; kt < 2; ++kt) {
        xA[2*kt]   = *(const float4*)(x + rowA * DIM + kt * 32 + g * 4);
        xA[2*kt+1] = *(const float4*)(x + rowA * DIM + kt * 32 + 16 + g * 4);
        xB[2*kt]   = *(const float4*)(x + rowB * DIM + kt * 32 + g * 4);
        xB[2*kt+1] = *(const float4*)(x + rowB * DIM + kt * 32 + 16 + g * 4);
    }
    __syncthreads();

    f16x8 bfragA[2], bfragB[2];
    #pragma unroll
    for (int kt = 0; kt < 2; ++kt) {
        frag_u ua, ub;
        ua.p[0] = __builtin_amdgcn_cvt_pkrtz(xA[2*kt].x,   xA[2*kt].y);
        ua.p[1] = __builtin_amdgcn_cvt_pkrtz(xA[2*kt].z,   xA[2*kt].w);
        ua.p[2] = __builtin_amdgcn_cvt_pkrtz(xA[2*kt+1].x, xA[2*kt+1].y);
        ua.p[3] = __builtin_amdgcn_cvt_pkrtz(xA[2*kt+1].z, xA[2*kt+1].w);
        bfragA[kt] = ua.v;
        ub.p[0] = __builtin_amdgcn_cvt_pkrtz(xB[2*kt].x,   xB[2*kt].y);
        ub.p[1] = __builtin_amdgcn_cvt_pkrtz(xB[2*kt].z,   xB[2*kt].w);
        ub.p[2] = __builtin_amdgcn_cvt_pkrtz(xB[2*kt+1].x, xB[2*kt+1].y);
        ub.p[3] = __builtin_amdgcn_cvt_pkrtz(xB[2*kt+1].z, xB[2*kt+1].w);
        bfragB[kt] = ub.v;
    }

    // ---------- initial: out0^T = W_down^T @ x^T + b_down (both chains) ----------
    f32x2 outA[4][2], outB[4][2];   // master fp32 state, C/D layout
    #pragma unroll
    for (int Mt = 0; Mt < 4; ++Mt) {
        const f32x4 bd = *(const f32x4*)(b_down + Mt * 16 + g * 4);
        f32x4 accA = bd, accB = bd;
        #pragma unroll
        for (int kt = 0; kt < 2; ++kt) {
            const f16x8 wfrag = *(const f16x8*)(wpre + (Mt * 2 + kt) * 512 + fbase);
            accA = __builtin_amdgcn_mfma_f32_16x16x32_f16(wfrag, bfragA[kt], accA, 0, 0, 0);
            accB = __builtin_amdgcn_mfma_f32_16x16x32_f16(wfrag, bfragB[kt], accB, 0, 0, 0);
        }
        outA[Mt][0][0] = accA[0]; outA[Mt][0][1] = accA[1];
        outA[Mt][1][0] = accA[2]; outA[Mt][1][1] = accA[3];
        outB[Mt][0][0] = accB[0]; outB[Mt][0][1] = accB[1];
        outB[Mt][1][0] = accB[2]; outB[Mt][1][1] = accB[3];
    }

    // refresh B fragments from state: 8 packed RTZ converts per chain
    auto refreshg = [&](f32x2 (&o2)[4][2], f16x8 (&bf)[2]) {
        #pragma unroll
        for (int kt = 0; kt < 2; ++kt) {
            frag_u u;
            u.p[0] = __builtin_amdgcn_cvt_pkrtz(o2[2*kt  ][0][0], o2[2*kt  ][0][1]);
            u.p[1] = __builtin_amdgcn_cvt_pkrtz(o2[2*kt  ][1][0], o2[2*kt  ][1][1]);
            u.p[2] = __builtin_amdgcn_cvt_pkrtz(o2[2*kt+1][0][0], o2[2*kt+1][0][1]);
            u.p[3] = __builtin_amdgcn_cvt_pkrtz(o2[2*kt+1][1][0], o2[2*kt+1][1][1]);
            bf[kt] = u.v;
        }
    };
    refreshg(outA, bfragA);
    refreshg(outB, bfragB);

    // ---------- head: logit = relu(out0@W1+b1)@W2 + b2 (padded, no masks) ----------
    const _Float16* w1pre = wpre + 8192;
    float partA = 0.0f, partB = 0.0f;
    #pragma unroll
    for (int Mt = 0; Mt < 7; ++Mt) {          // HID padded 100 -> 112
        const f32x4 b1v = *(const f32x4*)(b1p + Mt * 16 + g * 4);
        f32x4 accA = b1v, accB = b1v;
        #pragma unroll
        for (int kt = 0; kt < 2; ++kt) {
            const f16x8 wfrag = *(const f16x8*)(w1pre + (Mt * 2 + kt) * 512 + fbase);
            accA = __builtin_amdgcn_mfma_f32_16x16x32_f16(wfrag, bfragA[kt], accA, 0, 0, 0);
            accB = __builtin_amdgcn_mfma_f32_16x16x32_f16(wfrag, bfragB[kt], accB, 0, 0, 0);
        }
        #pragma unroll
        for (int reg = 0; reg < 4; ++reg) {
            const float w2v = w2p[Mt * 16 + g * 4 + reg];
            partA += fmaxf(accA[reg], 0.0f) * w2v;
            partB += fmaxf(accB[reg], 0.0f) * w2v;
        }
    }
    partA += __shfl_xor(partA, 16); partA += __shfl_xor(partA, 32);
    partB += __shfl_xor(partB, 16); partB += __shfl_xor(partB, 32);
    const float sfac = 0.5f * powf(0.04f, 1.0f / 1.8f);
    const float scaleA = sfac / (1.0f + expf(-(partA + b2[0])));
    const float scaleB = sfac / (1.0f + expf(-(partB + b2[0])));
    const f32x2 scA = { scaleA, scaleA };
    const f32x2 scB = { scaleB, scaleB };
    const f32x2 c104 = { 1.04f, 1.04f };
    const f32x2 zero2 = { 0.0f, 0.0f };

    // ---------- persistent dt-scaled drift fragments + dt*bias (registers) ----------
    f16x8 aWd[4][2];
    #pragma unroll
    for (int Mt = 0; Mt < 4; ++Mt)
        #pragma unroll
        for (int kt = 0; kt < 2; ++kt)
            aWd[Mt][kt] = *(const f16x8*)(wpre + 4096 + (Mt * 2 + kt) * 512 + fbase);

    f32x4 biasd[4];
    #pragma unroll
    for (int Mt = 0; Mt < 4; ++Mt) {
        f32x4 b = *(const f32x4*)(b_drift + Mt * 16 + g * 4);
        biasd[Mt][0] = b[0] * dt; biasd[Mt][1] = b[1] * dt;
        biasd[Mt][2] = b[2] * dt; biasd[Mt][3] = b[3] * dt;
    }

    auto stepelt = [&](f32x2 (&o2)[4][2], f32x4 (&ac)[4], f32x4 (&nzv)[4],
                       const f32x2& sc2) {
        #pragma unroll
        for (int Mt = 0; Mt < 4; ++Mt) {
            #pragma unroll
            for (int h = 0; h < 2; ++h) {
                f32x2 a2 = { ac[Mt][2*h], ac[Mt][2*h+1] };
                f32x2 n2 = { nzv[Mt][2*h], nzv[Mt][2*h+1] };
                f32x2 rel = __builtin_elementwise_max(a2, zero2);
                f32x2 tmp = __builtin_elementwise_fma(o2[Mt][h], c104, rel);
                o2[Mt][h] = __builtin_elementwise_fma(sc2, n2, tmp);
            }
        }
    };

    // ---------- 25 SDE steps, two interleaved chains ----------
    #pragma unroll 5
    for (int t = 0; t < DEPTH; ++t) {
        f32x4 nz[4];   // shared by both chains (noise is row-independent)
        #pragma unroll
        for (int Mt = 0; Mt < 4; ++Mt)
            nz[Mt] = *(const f32x4*)(noise_lds + t * DIM + Mt * 16 + g * 4);

        f32x4 accA[4], accB[4];
        #pragma unroll
        for (int Mt = 0; Mt < 4; ++Mt) {
            accA[Mt] = __builtin_amdgcn_mfma_f32_16x16x32_f16(
                aWd[Mt][0], bfragA[0], biasd[Mt], 0, 0, 0);
            accA[Mt] = __builtin_amdgcn_mfma_f32_16x16x32_f16(
                aWd[Mt][1], bfragA[1], accA[Mt], 0, 0, 0);
        }
        #pragma unroll
        for (int Mt = 0; Mt < 4; ++Mt) {
            accB[Mt] = __builtin_amdgcn_mfma_f32_16x16x32_f16(
                aWd[Mt][0], bfragB[0], biasd[Mt], 0, 0, 0);
            accB[Mt] = __builtin_amdgcn_mfma_f32_16x16x32_f16(
                aWd[Mt][1], bfragB[1], accB[Mt], 0, 0, 0);
        }
        stepelt(outA, accA, nz, scA);  refreshg(outA, bfragA);
        stepelt(outB, accB, nz, scB);  refreshg(outB, bfragB);
    }

    // ---- final drift (undo dt scaling: relu(z) = relu(dt*z)*25) + stores ----
    const long long out2_off = (long long)batch * DIM;
    #pragma unroll
    for (int Mt = 0; Mt < 4; ++Mt) {
        f32x4 accA = __builtin_amdgcn_mfma_f32_16x16x32_f16(
            aWd[Mt][0], bfragA[0], biasd[Mt], 0, 0, 0);
        accA = __builtin_amdgcn_mfma_f32_16x16x32_f16(
            aWd[Mt][1], bfragA[1], accA, 0, 0, 0);
        f32x4 accB = __builtin_amdgcn_mfma_f32_16x16x32_f16(
            aWd[Mt][0], bfragB[0], biasd[Mt], 0, 0, 0);
        accB = __builtin_amdgcn_mfma_f32_16x16x32_f16(
            aWd[Mt][1], bfragB[1], accB, 0, 0, 0);

        float4 dv, ov;
        ov.x = outA[Mt][0][0]; ov.y = outA[Mt][0][1];
        ov.z = outA[Mt][1][0]; ov.w = outA[Mt][1][1];
        dv.x = fmaf(fmaxf(accA[0], 0.0f), 25.0f, ov.x);
        dv.y = fmaf(fmaxf(accA[1], 0.0f), 25.0f, ov.y);
        dv.z = fmaf(fmaxf(accA[2], 0.0f), 25.0f, ov.z);
        dv.w = fmaf(fmaxf(accA[3], 0.0f), 25.0f, ov.w);
        *(float4*)(out + (long long)rowA * DIM + Mt * 16 + g * 4) = dv;
        *(float4*)(out + out2_off + (long long)rowA * DIM + Mt * 16 + g * 4) = ov;

        ov.x = outB[Mt][0][0]; ov.y = outB[Mt][0][1];
        ov.z = outB[Mt][1][0]; ov.w = outB[Mt][1][1];
        dv.x = fmaf(fmaxf(accB[0], 0.0f), 25.0f, ov.x);
        dv.y = fmaf(fmaxf(accB[1], 0.0f), 25.0f, ov.y);
        dv.z = fmaf(fmaxf(accB[2], 0.0f), 25.0f, ov.z);
        dv.w = fmaf(fmaxf(accB[3], 0.0f), 25.0f, ov.w);
        *(float4*)(out + (long long)rowB * DIM + Mt * 16 + g * 4) = dv;
        *(float4*)(out + out2_off + (long long)rowB * DIM + Mt * 16 + g * 4) = ov;
    }
}

// ============== FALLBACK path (round-4 kernel, in-block staging) ==============
__global__ __launch_bounds__(256, 4) void sdenet_fused_fb(
    const float* __restrict__ x,      const float* __restrict__ noise_g,
    const float* __restrict__ W_down, const float* __restrict__ b_down,
    const float* __restrict__ W_drift,const float* __restrict__ b_drift,
    const float* __restrict__ W1,     const float* __restrict__ b1,
    const float* __restrict__ W2,     const float* __restrict__ b2,
    float* __restrict__ out, int batch)
{
    __shared__ float    noise_lds[DEPTH * DIM];
    __shared__ float    bias_lds[DIM];
    __shared__ _Float16 wdown[4096];
    __shared__ _Float16 wdrift[4096];
    __shared__ _Float16 w1buf[7168];

    const int tid  = threadIdx.x;
    const int wave = tid >> 6;
    const int lane = tid & 63;
    const int r    = lane & 15;
    const int g    = lane >> 4;
    const int row  = blockIdx.x * 64 + wave * 16 + r;
    const int fbase = lane * 8;
    const float dt = 0.04f;

    {
        const float4* src = (const float4*)noise_g;
        float4* dst = (float4*)noise_lds;
        #pragma unroll
        for (int it = 0; it < 2; ++it) {
            int idx = tid + it * 256;
            if (idx < DEPTH * DIM / 4) dst[idx] = src[idx];
        }
    }
    if (tid < DIM) bias_lds[tid] = dt * b_drift[tid];

    for (int idx2 = tid; idx2 < 2048; idx2 += 256) {
        const int fi    = idx2 >> 8;
        const int lane2 = (idx2 >> 2) & 63;
        const int j     = (idx2 & 3) * 2;
        const int m     = (fi >> 1) * 16 + (lane2 & 15);
        const int k     = (fi & 1) * 32 + ((j & 4) ? 16 : 0)
                        + (lane2 >> 4) * 4 + (j & 3);
        *(h2*)(wdown + idx2 * 2) =
            __builtin_amdgcn_cvt_pkrtz(W_down[k * DIM + m],
                                       W_down[(k + 1) * DIM + m]);
        *(h2*)(wdrift + idx2 * 2) =
            __builtin_amdgcn_cvt_pkrtz(dt * W_drift[k * DIM + m],
                                       dt * W_drift[(k + 1) * DIM + m]);
    }
    for (int idx2 = tid; idx2 < 3584; idx2 += 256) {
        const int fi    = idx2 >> 8;
        const int lane2 = (idx2 >> 2) & 63;
        const int j     = (idx2 & 3) * 2;
        const int n     = (fi >> 1) * 16 + (lane2 & 15);
        const int k     = (fi & 1) * 32 + ((j & 4) ? 16 : 0)
                        + (lane2 >> 4) * 4 + (j & 3);
        const float v0 = (n < HID) ? W1[k * HID + n] : 0.0f;
        const float v1 = (n < HID) ? W1[(k + 1) * HID + n] : 0.0f;
        *(h2*)(w1buf + idx2 * 2) = __builtin_amdgcn_cvt_pkrtz(v0, v1);
    }

    float4 xlo[2], xhi[2];
    #pragma unroll
    for (int kt = 0; kt < 2; ++kt) {
        xlo[kt] = *(const float4*)(x + row * DIM + kt * 32 + g * 4);
        xhi[kt] = *(const float4*)(x + row * DIM + kt * 32 + 16 + g * 4);
    }
    __syncthreads();

    f16x8 bfrag[2];
    #pragma unroll
    for (int kt = 0; kt < 2; ++kt) {
        frag_u u;
        u.p[0] = __builtin_amdgcn_cvt_pkrtz(xlo[kt].x, xlo[kt].y);
        u.p[1] = __builtin_amdgcn_cvt_pkrtz(xlo[kt].z, xlo[kt].w);
        u.p[2] = __builtin_amdgcn_cvt_pkrtz(xhi[kt].x, xhi[kt].y);
        u.p[3] = __builtin_amdgcn_cvt_pkrtz(xhi[kt].z, xhi[kt].w);
        bfrag[kt] = u.v;
    }

    f32x2 out2[4][2];
    #pragma unroll
    for (int Mt = 0; Mt < 4; ++Mt) {
        f32x4 acc = *(const f32x4*)(b_down + Mt * 16 + g * 4);
        #pragma unroll
        for (int kt = 0; kt < 2; ++kt)
            acc = __builtin_amdgcn_mfma_f32_16x16x32_f16(
                *(const f16x8*)(wdown + (Mt * 2 + kt) * 512 + fbase),
                bfrag[kt], acc, 0, 0, 0);
        out2[Mt][0][0] = acc[0]; out2[Mt][0][1] = acc[1];
        out2[Mt][1][0] = acc[2]; out2[Mt][1][1] = acc[3];
    }

    auto refresh = [&]() {
        #pragma unroll
        for (int kt = 0; kt < 2; ++kt) {
            frag_u u;
            u.p[0] = __builtin_amdgcn_cvt_pkrtz(out2[2*kt  ][0][0], out2[2*kt  ][0][1]);
            u.p[1] = __builtin_amdgcn_cvt_pkrtz(out2[2*kt  ][1][0], out2[2*kt  ][1][1]);
            u.p[2] = __builtin_amdgcn_cvt_pkrtz(out2[2*kt+1][0][0], out2[2*kt+1][0][1]);
            u.p[3] = __builtin_amdgcn_cvt_pkrtz(out2[2*kt+1][1][0], out2[2*kt+1][1][1]);
            bfrag[kt] = u.v;
        }
    };
    refresh();

    float partial = 0.0f;
    #pragma unroll
    for (int Mt = 0; Mt < 7; ++Mt) {
        f32x4 acc;
        #pragma unroll
        for (int reg = 0; reg < 4; ++reg) {
            const int n = Mt * 16 + g * 4 + reg;
            acc[reg] = (n < HID) ? b1[n] : 0.0f;
        }
        #pragma unroll
        for (int kt = 0; kt < 2; ++kt)
            acc = __builtin_amdgcn_mfma_f32_16x16x32_f16(
                *(const f16x8*)(w1buf + (Mt * 2 + kt) * 512 + fbase),
                bfrag[kt], acc, 0, 0, 0);
        #pragma unroll
        for (int reg = 0; reg < 4; ++reg) {
            const int n = Mt * 16 + g * 4 + reg;
            if (n < HID) partial += fmaxf(acc[reg], 0.0f) * W2[n];
        }
    }
    partial += __shfl_xor(partial, 16);
    partial += __shfl_xor(partial, 32);
    const float logit = partial + b2[0];
    const float scale = 0.5f * (1.0f / (1.0f + expf(-logit)))
                      * powf(0.04f, 1.0f / 1.8f);
    const f32x2 scale2 = { scale, scale };
    const f32x2 c104   = { 1.04f, 1.04f };
    const f32x2 zero2  = { 0.0f, 0.0f };

    f16x8 aWd[4][2];
    #pragma unroll
    for (int Mt = 0; Mt < 4; ++Mt)
        #pragma unroll
        for (int kt = 0; kt < 2; ++kt)
            aWd[Mt][kt] = *(const f16x8*)(wdrift + (Mt * 2 + kt) * 512 + fbase);

    #pragma unroll
    for (int t = 0; t < DEPTH; ++t) {
        f32x4 nz[4];
        #pragma unroll
        for (int Mt = 0; Mt < 4; ++Mt)
            nz[Mt] = *(const f32x4*)(noise_lds + t * DIM + Mt * 16 + g * 4);

        f32x4 acc[4];
        #pragma unroll
        for (int Mt = 0; Mt < 4; ++Mt) {
            acc[Mt] = *(const f32x4*)(bias_lds + Mt * 16 + g * 4);
            acc[Mt] = __builtin_amdgcn_mfma_f32_16x16x32_f16(
                aWd[Mt][0], bfrag[0], acc[Mt], 0, 0, 0);
            acc[Mt] = __builtin_amdgcn_mfma_f32_16x16x32_f16(
                aWd[Mt][1], bfrag[1], acc[Mt], 0, 0, 0);
        }
        #pragma unroll
        for (int Mt = 0; Mt < 4; ++Mt) {
            #pragma unroll
            for (int h = 0; h < 2; ++h) {
                f32x2 a2 = { acc[Mt][2*h], acc[Mt][2*h+1] };
                f32x2 n2 = { nz[Mt][2*h],  nz[Mt][2*h+1] };
                f32x2 rel = __builtin_elementwise_max(a2, zero2);
                f32x2 tmp = __builtin_elementwise_fma(out2[Mt][h], c104, rel);
                out2[Mt][h] = __builtin_elementwise_fma(scale2, n2, tmp);
            }
        }
        refresh();
    }

    const long long out2_off = (long long)batch * DIM;
    #pragma unroll
    for (int Mt = 0; Mt < 4; ++Mt) {
        f32x4 acc = *(const f32x4*)(bias_lds + Mt * 16 + g * 4);
        acc = __builtin_amdgcn_mfma_f32_16x16x32_f16(
            aWd[Mt][0], bfrag[0], acc, 0, 0, 0);
        acc = __builtin_amdgcn_mfma_f32_16x16x32_f16(
            aWd[Mt][1], bfrag[1], acc, 0, 0, 0);
        float o0 = out2[Mt][0][0], o1 = out2[Mt][0][1];
        float o2 = out2[Mt][1][0], o3 = out2[Mt][1][1];
        float4 dv, ov;
        dv.x = fmaf(fmaxf(acc[0], 0.0f), 25.0f, o0);
        dv.y = fmaf(fmaxf(acc[1], 0.0f), 25.0f, o1);
        dv.z = fmaf(fmaxf(acc[2], 0.0f), 25.0f, o2);
        dv.w = fmaf(fmaxf(acc[3], 0.0f), 25.0f, o3);
        ov.x = o0; ov.y = o1; ov.z = o2; ov.w = o3;
        *(float4*)(out + (long long)row * DIM + Mt * 16 + g * 4) = dv;
        *(float4*)(out + out2_off + (long long)row * DIM + Mt * 16 + g * 4) = ov;
    }
}

extern "C" void kernel_launch(void* const* d_in, const int* in_sizes, int n_in,
                              void* d_out, int out_size, void* d_ws, size_t ws_size,
                              hipStream_t stream) {
    const float* x       = (const float*)d_in[0];
    const float* u_raw   = (const float*)d_in[1];
    const float* w_raw   = (const float*)d_in[2];
    const float* W_down  = (const float*)d_in[3];
    const float* b_down  = (const float*)d_in[4];
    const float* W_drift = (const float*)d_in[5];
    const float* b_drift = (const float*)d_in[6];
    const float* W1      = (const float*)d_in[7];
    const float* b1      = (const float*)d_in[8];
    const float* W2      = (const float*)d_in[9];
    const float* b2      = (const float*)d_in[10];
    float* out   = (float*)d_out;

    // workspace layout: [0,6400) noise f32 | [6400,37120) wpre f16 |
    //                   [37120,37568) b1p  | [37568,38016) w2p
    float*     noise = (float*)d_ws;
    _Float16*  wpre  = (_Float16*)((char*)d_ws + 6400);
    float*     b1p   = (float*)((char*)d_ws + 37120);
    float*     w2p   = (float*)((char*)d_ws + 37568);

    const int batch = in_sizes[0] / DIM;       // 262144

    if (ws_size >= 38016) {
        prep_kernel<<<38, 256, 0, stream>>>(u_raw, w_raw, W_down, W_drift,
                                            W1, b1, W2, noise, wpre, b1p, w2p);
        sdenet_fused_pre2<<<batch / 128, 256, 0, stream>>>(
            x, noise, wpre, b_down, b_drift, b1p, w2p, b2, out, batch);
    } else {
        // levy noise via prep_kernel's noise range only (first 7 blocks cover 1600)
        prep_kernel<<<7, 256, 0, stream>>>(u_raw, w_raw, W_down, W_drift,
                                           W1, b1, W2, noise,
                                           (_Float16*)noise, noise, noise); // unused paths OOB-guarded by grid
        sdenet_fused_fb<<<batch / 64, 256, 0, stream>>>(
            x, noise, W_down, b_down, W_drift, b_drift,
            W1, b1, W2, b2, out, batch);
    }
}